// Round 1
// baseline (206.846 us; speedup 1.0000x reference)
//
#include <hip/hip_runtime.h>

#define DEV static __device__ __forceinline__

typedef __attribute__((ext_vector_type(4))) float f32x4;
typedef __attribute__((ext_vector_type(8))) __bf16 bfv8;
typedef __attribute__((ext_vector_type(8))) short s8v;
typedef __attribute__((ext_vector_type(4))) short s4v;

DEV short f2bf(float f) {
    unsigned u = __float_as_uint(f);
    u = (u + 0x7fffu + ((u >> 16) & 1u)) >> 16;
    return (short)u;
}
DEV float bf2f(short s) { return __uint_as_float(((unsigned)(unsigned short)s) << 16); }

DEV void gload16(const void* g, void* l) {
    __builtin_amdgcn_global_load_lds(
        (const __attribute__((address_space(1))) void*)g,
        (__attribute__((address_space(3))) void*)l, 16, 0, 0);
}

DEV f32x4 mfma16(bfv8 a, bfv8 b, f32x4 c) {
    return __builtin_amdgcn_mfma_f32_16x16x32_bf16(a, b, c, 0, 0, 0);
}

// LDS tile layout: [row][8 slots of 8 bf16], physical slot = logical slot ^ (row&7)
DEV bfv8 ldsfrag(const short* base, int row, int slog) {
    int sp = slog ^ (row & 7);
    return *reinterpret_cast<const bfv8*>(base + row * 64 + sp * 8);
}

// ---------------- f32 -> bf16 elementwise (8 elems/thread, exact-fit grid) ----
__global__ void k_cvt(const float* __restrict__ in, short* __restrict__ out, float s) {
    int i = blockIdx.x * blockDim.x + threadIdx.x;
    const float4* p = (const float4*)in + (size_t)i * 2;
    float4 a = p[0], b = p[1];
    s8v o;
    o[0] = f2bf(a.x * s); o[1] = f2bf(a.y * s); o[2] = f2bf(a.z * s); o[3] = f2bf(a.w * s);
    o[4] = f2bf(b.x * s); o[5] = f2bf(b.y * s); o[6] = f2bf(b.z * s); o[7] = f2bf(b.w * s);
    reinterpret_cast<s8v*>(out)[i] = o;
}

// ---------------- W [1024x1024] f32 (k-major) -> Wt [n][k] bf16 ----------------
__global__ void k_transpose(const float* __restrict__ W, short* __restrict__ Wt, float s) {
    __shared__ float tl[32][33];
    int tx = threadIdx.x & 31, ty = threadIdx.x >> 5;
    int nb = blockIdx.x * 32, kb = blockIdx.y * 32;
#pragma unroll
    for (int i = 0; i < 4; i++)
        tl[ty + i * 8][tx] = W[(kb + ty + i * 8) * 1024 + nb + tx];
    __syncthreads();
#pragma unroll
    for (int i = 0; i < 4; i++)
        Wt[(nb + ty + i * 8) * 1024 + kb + tx] = f2bf(tl[tx][ty + i * 8] * s);
}

// ---------------- GEMM: C[4096x1024] = A[4096x1024] @ Bt^T (+bias) -------------
// A row-major bf16, Bt: [n][k] bf16.  BM=64 BN=128 BK=64, 4 waves (2Mx2N).
// epi 0: bf16 out [B,H,S,Hd]; epi 1: bf16 out [B,H,Hd,S] (V^T); epi 2: f32 row-major.
__global__ __launch_bounds__(256, 2) void k_gemm(
    const short* __restrict__ A, const short* __restrict__ Bt,
    const float* __restrict__ bias, void* __restrict__ outp,
    float bscale, int epi)
{
    __shared__ alignas(16) short As[64 * 64];
    __shared__ alignas(16) short Bs[128 * 64];
    const int t = threadIdx.x, lane = t & 63;
    const int wv = t >> 6, wr = wv >> 1, wc = wv & 1;
    const int g = lane >> 4, c = lane & 15;
    const int row0 = blockIdx.x * 64, col0 = blockIdx.y * 128;

    const f32x4 z4 = {0.f, 0.f, 0.f, 0.f};
    f32x4 acc[2][4];
#pragma unroll
    for (int m = 0; m < 2; m++)
#pragma unroll
        for (int n = 0; n < 4; n++) acc[m][n] = z4;

    for (int kt = 0; kt < 16; ++kt) {
        const int k0 = kt * 64;
        const short* Ag = A + row0 * 1024 + k0;
        const short* Bg = Bt + col0 * 1024 + k0;
#pragma unroll
        for (int j = 0; j < 2; j++) {
            int idx = j * 256 + t;
            int row = idx >> 3, sp = idx & 7, sl = sp ^ (row & 7);
            gload16(Ag + row * 1024 + sl * 8, As + idx * 8);
        }
#pragma unroll
        for (int j = 0; j < 4; j++) {
            int idx = j * 256 + t;
            int row = idx >> 3, sp = idx & 7, sl = sp ^ (row & 7);
            gload16(Bg + row * 1024 + sl * 8, Bs + idx * 8);
        }
        __syncthreads();

        bfv8 af[2][2], bfr[4][2];
#pragma unroll
        for (int m = 0; m < 2; m++)
#pragma unroll
            for (int ks = 0; ks < 2; ks++)
                af[m][ks] = ldsfrag(As, wr * 32 + m * 16 + c, ks * 4 + g);
#pragma unroll
        for (int n = 0; n < 4; n++)
#pragma unroll
            for (int ks = 0; ks < 2; ks++)
                bfr[n][ks] = ldsfrag(Bs, wc * 64 + n * 16 + c, ks * 4 + g);
#pragma unroll
        for (int m = 0; m < 2; m++)
#pragma unroll
            for (int n = 0; n < 4; n++)
#pragma unroll
                for (int ks = 0; ks < 2; ks++)
                    acc[m][n] = mfma16(af[m][ks], bfr[n][ks], acc[m][n]);
        __syncthreads();
    }

    // epilogue: C row = row0 + wr*32 + m*16 + g*4 + r ; col = col0 + wc*64 + n*16 + c
#pragma unroll
    for (int n = 0; n < 4; n++) {
        const int gc = col0 + wc * 64 + n * 16 + c;
        const float bvl = bias[gc] * bscale;
        const int h = gc >> 6, d = gc & 63;
#pragma unroll
        for (int m = 0; m < 2; m++) {
            const int gr = row0 + wr * 32 + m * 16 + g * 4;
            if (epi == 2) {
                float* O = (float*)outp;
#pragma unroll
                for (int r = 0; r < 4; r++) O[(gr + r) * 1024 + gc] = acc[m][n][r] + bvl;
            } else {
                const int b = gr >> 11, sr = gr & 2047;
                short* O = (short*)outp;
                if (epi == 0) {
                    int base = ((b * 16 + h) * 2048 + sr) * 64 + d;
#pragma unroll
                    for (int r = 0; r < 4; r++) O[base + r * 64] = f2bf(acc[m][n][r] + bvl);
                } else {
                    s4v vv;
#pragma unroll
                    for (int r = 0; r < 4; r++) vv[r] = f2bf(acc[m][n][r] + bvl);
                    *reinterpret_cast<s4v*>(O + ((b * 16 + h) * 64 + d) * 2048 + sr) = vv;
                }
            }
        }
    }
}

// ---------------- flash attention with additive binding bias -------------------
// Q,K: [B,H,S,64] bf16 (Q pre-scaled), Vt: [B,H,64,S] bf16, bb: 0.5*binding bf16 [S,S]
// Ob: [B,S,1024] bf16. Grid: (S/128, B*H). 4 waves x 32 q-rows. KV tile = 64.
__global__ __launch_bounds__(256, 2) void k_attn(
    const short* __restrict__ Q, const short* __restrict__ K,
    const short* __restrict__ Vt, const short* __restrict__ bb,
    short* __restrict__ Ob)
{
    __shared__ alignas(16) short Ks[64 * 64];
    __shared__ alignas(16) short Vs[64 * 64];
    __shared__ alignas(16) short Ps[4][32 * 64];
    const int t = threadIdx.x, lane = t & 63;
    const int wv = t >> 6, g = lane >> 4, c = lane & 15;
    const int qt = blockIdx.x, bh = blockIdx.y;
    const int b = bh >> 4, h = bh & 15;
    const short* Qb = Q + bh * 2048 * 64;
    const short* Kb = K + bh * 2048 * 64;
    const short* Vb = Vt + bh * 64 * 2048;
    const int q0 = qt * 128 + wv * 32;

    bfv8 qf[2][2];
#pragma unroll
    for (int m = 0; m < 2; m++)
#pragma unroll
        for (int ks = 0; ks < 2; ks++)
            qf[m][ks] = *reinterpret_cast<const bfv8*>(Qb + (q0 + m * 16 + c) * 64 + ks * 32 + g * 8);

    const f32x4 z4 = {0.f, 0.f, 0.f, 0.f};
    f32x4 oa[2][4];
    float mrun[2][4], lrun[2][4];
#pragma unroll
    for (int m = 0; m < 2; m++) {
#pragma unroll
        for (int n = 0; n < 4; n++) oa[m][n] = z4;
#pragma unroll
        for (int r = 0; r < 4; r++) { mrun[m][r] = -3.0e38f; lrun[m][r] = 0.f; }
    }

    for (int kt = 0; kt < 32; ++kt) {
        const int kk0 = kt * 64;
#pragma unroll
        for (int j = 0; j < 2; j++) {
            int idx = j * 256 + t;
            int row = idx >> 3, sp = idx & 7, sl = sp ^ (row & 7);
            gload16(Kb + (kk0 + row) * 64 + sl * 8, Ks + idx * 8);
            gload16(Vb + row * 2048 + kk0 + sl * 8, Vs + idx * 8);
        }
        __syncthreads();

        // S = Q K^T (Q pre-scaled by SCALE)
        f32x4 sc[2][4];
#pragma unroll
        for (int m = 0; m < 2; m++)
#pragma unroll
            for (int n = 0; n < 4; n++) sc[m][n] = z4;
        bfv8 kf[4][2];
#pragma unroll
        for (int n = 0; n < 4; n++)
#pragma unroll
            for (int ks = 0; ks < 2; ks++)
                kf[n][ks] = ldsfrag(Ks, n * 16 + c, ks * 4 + g);
#pragma unroll
        for (int m = 0; m < 2; m++)
#pragma unroll
            for (int n = 0; n < 4; n++)
#pragma unroll
                for (int ks = 0; ks < 2; ks++)
                    sc[m][n] = mfma16(qf[m][ks], kf[n][ks], sc[m][n]);

        // + 0.5*binding  (C-frag: row=(g*4+r), col=c within 16-tile)
#pragma unroll
        for (int m = 0; m < 2; m++)
#pragma unroll
            for (int r = 0; r < 4; r++) {
                const short* bq_ = bb + (q0 + m * 16 + g * 4 + r) * 2048 + kk0 + c;
#pragma unroll
                for (int n = 0; n < 4; n++)
                    sc[m][n][r] += bf2f(bq_[n * 16]);
            }

        // online softmax (row stats replicated across 16-lane groups)
#pragma unroll
        for (int m = 0; m < 2; m++) {
            float pm[4];
#pragma unroll
            for (int r = 0; r < 4; r++)
                pm[r] = fmaxf(fmaxf(sc[m][0][r], sc[m][1][r]), fmaxf(sc[m][2][r], sc[m][3][r]));
#pragma unroll
            for (int off = 1; off < 16; off <<= 1)
#pragma unroll
                for (int r = 0; r < 4; r++)
                    pm[r] = fmaxf(pm[r], __shfl_xor(pm[r], off));
#pragma unroll
            for (int r = 0; r < 4; r++) {
                const float mn = fmaxf(mrun[m][r], pm[r]);
                const float corr = __expf(mrun[m][r] - mn);
                mrun[m][r] = mn;
                float rs = 0.f;
#pragma unroll
                for (int n = 0; n < 4; n++) {
                    float p = __expf(sc[m][n][r] - mn);
                    sc[m][n][r] = p;
                    rs += p;
                }
#pragma unroll
                for (int off = 1; off < 16; off <<= 1)
                    rs += __shfl_xor(rs, off);
                lrun[m][r] = lrun[m][r] * corr + rs;
#pragma unroll
                for (int n = 0; n < 4; n++) oa[m][n][r] *= corr;
            }
        }

        // P (C-layout) -> per-wave swizzled LDS -> A-layout fragments
        short* Pw = &Ps[wv][0];
#pragma unroll
        for (int m = 0; m < 2; m++)
#pragma unroll
            for (int n = 0; n < 4; n++)
#pragma unroll
                for (int r = 0; r < 4; r++) {
                    int row = m * 16 + g * 4 + r, col = n * 16 + c;
                    Pw[row * 64 + (((col >> 3) ^ (row & 7)) << 3) + (col & 7)] = f2bf(sc[m][n][r]);
                }
        bfv8 pa[2][2], vf[4][2];
#pragma unroll
        for (int m = 0; m < 2; m++)
#pragma unroll
            for (int ks = 0; ks < 2; ks++)
                pa[m][ks] = ldsfrag(Pw, m * 16 + c, ks * 4 + g);
#pragma unroll
        for (int n = 0; n < 4; n++)
#pragma unroll
            for (int ks = 0; ks < 2; ks++)
                vf[n][ks] = ldsfrag(Vs, n * 16 + c, ks * 4 + g);
#pragma unroll
        for (int m = 0; m < 2; m++)
#pragma unroll
            for (int n = 0; n < 4; n++)
#pragma unroll
                for (int ks = 0; ks < 2; ks++)
                    oa[m][n] = mfma16(pa[m][ks], vf[n][ks], oa[m][n]);
        __syncthreads();
    }

    // write O/l -> Ob [B,S,1024] bf16
#pragma unroll
    for (int m = 0; m < 2; m++)
#pragma unroll
        for (int n = 0; n < 4; n++) {
            const int col = h * 64 + n * 16 + c;
#pragma unroll
            for (int r = 0; r < 4; r++) {
                const int sr = q0 + m * 16 + g * 4 + r;
                Ob[(b * 2048 + sr) * 1024 + col] = f2bf(oa[m][n][r] / lrun[m][r]);
            }
        }
}

extern "C" void kernel_launch(void* const* d_in, const int* in_sizes, int n_in,
                              void* d_out, int out_size, void* d_ws, size_t ws_size,
                              hipStream_t stream)
{
    (void)in_sizes; (void)n_in; (void)out_size; (void)ws_size;
    const float* x    = (const float*)d_in[0];
    const float* bind = (const float*)d_in[1];
    const float* Wq   = (const float*)d_in[2];
    const float* bq   = (const float*)d_in[3];
    const float* Wk   = (const float*)d_in[4];
    const float* bk   = (const float*)d_in[5];
    const float* Wv   = (const float*)d_in[6];
    const float* bv   = (const float*)d_in[7];
    const float* Wo   = (const float*)d_in[8];
    const float* bo   = (const float*)d_in[9];

    char* ws = (char*)d_ws;
    const size_t MB = (size_t)1 << 20;
    short* xb   = (short*)(ws + 0 * MB);   // 8 MiB  x as bf16
    short* Wqt  = (short*)(ws + 8 * MB);   // 2 MiB  each, [n][k] bf16
    short* Wkt  = (short*)(ws + 10 * MB);
    short* Wvt  = (short*)(ws + 12 * MB);
    short* Wot  = (short*)(ws + 14 * MB);
    short* bbm  = (short*)(ws + 16 * MB);  // 8 MiB  0.5*binding bf16
    short* Qs   = (short*)(ws + 24 * MB);  // 8 MiB  [B,H,S,64]
    short* Kst  = (short*)(ws + 32 * MB);  // 8 MiB  [B,H,S,64]
    short* Vts  = (short*)(ws + 40 * MB);  // 8 MiB  [B,H,64,S]
    short* Obuf = (short*)(ws + 48 * MB);  // 8 MiB  [B,S,1024]

    const float SC = 0.125f;  // 64^-0.5, folded into Wq/bq (exact pow2)

    k_cvt<<<2048, 256, 0, stream>>>(x, xb, 1.f);
    k_cvt<<<2048, 256, 0, stream>>>(bind, bbm, 0.5f);
    k_transpose<<<dim3(32, 32), 256, 0, stream>>>(Wq, Wqt, SC);
    k_transpose<<<dim3(32, 32), 256, 0, stream>>>(Wk, Wkt, 1.f);
    k_transpose<<<dim3(32, 32), 256, 0, stream>>>(Wv, Wvt, 1.f);
    k_transpose<<<dim3(32, 32), 256, 0, stream>>>(Wo, Wot, 1.f);
    k_gemm<<<dim3(64, 8), 256, 0, stream>>>(xb, Wqt, bq, Qs, SC, 0);
    k_gemm<<<dim3(64, 8), 256, 0, stream>>>(xb, Wkt, bk, Kst, 1.f, 0);
    k_gemm<<<dim3(64, 8), 256, 0, stream>>>(xb, Wvt, bv, Vts, 1.f, 1);
    k_attn<<<dim3(16, 32), 256, 0, stream>>>(Qs, Kst, Vts, bbm, Obuf);
    k_gemm<<<dim3(64, 8), 256, 0, stream>>>(Obuf, Wot, bo, d_out, 1.f, 2);
}

// Round 2
// 176.242 us; speedup vs baseline: 1.1736x; 1.1736x over previous
//
#include <hip/hip_runtime.h>

#define DEV static __device__ __forceinline__

typedef __attribute__((ext_vector_type(4))) float f32x4;
typedef __attribute__((ext_vector_type(8))) __bf16 bfv8;
typedef __attribute__((ext_vector_type(8))) short s8v;
typedef __attribute__((ext_vector_type(4))) short s4v;

DEV short f2bf(float f) {
    unsigned u = __float_as_uint(f);
    u = (u + 0x7fffu + ((u >> 16) & 1u)) >> 16;
    return (short)u;
}
DEV float bf2f(short s) { return __uint_as_float(((unsigned)(unsigned short)s) << 16); }

DEV void gload16(const void* g, void* l) {
    __builtin_amdgcn_global_load_lds(
        (const __attribute__((address_space(1))) void*)g,
        (__attribute__((address_space(3))) void*)l, 16, 0, 0);
}

DEV f32x4 mfma16(bfv8 a, bfv8 b, f32x4 c) {
    return __builtin_amdgcn_mfma_f32_16x16x32_bf16(a, b, c, 0, 0, 0);
}

// LDS tile layout: [row][8 slots of 8 bf16], physical slot = logical slot ^ (row&7)
DEV bfv8 ldsfrag(const short* base, int row, int slog) {
    int sp = slog ^ (row & 7);
    return *reinterpret_cast<const bfv8*>(base + row * 64 + sp * 8);
}

// ---------------- f32 -> bf16 elementwise (8 elems/thread, exact-fit grid) ----
__global__ void k_cvt(const float* __restrict__ in, short* __restrict__ out, float s) {
    int i = blockIdx.x * blockDim.x + threadIdx.x;
    const float4* p = (const float4*)in + (size_t)i * 2;
    float4 a = p[0], b = p[1];
    s8v o;
    o[0] = f2bf(a.x * s); o[1] = f2bf(a.y * s); o[2] = f2bf(a.z * s); o[3] = f2bf(a.w * s);
    o[4] = f2bf(b.x * s); o[5] = f2bf(b.y * s); o[6] = f2bf(b.z * s); o[7] = f2bf(b.w * s);
    reinterpret_cast<s8v*>(out)[i] = o;
}

// ---------------- W [1024x1024] f32 (k-major) -> Wt [n][k] bf16 ----------------
__global__ void k_transpose(const float* __restrict__ W, short* __restrict__ Wt, float s) {
    __shared__ float tl[32][33];
    int tx = threadIdx.x & 31, ty = threadIdx.x >> 5;
    int nb = blockIdx.x * 32, kb = blockIdx.y * 32;
#pragma unroll
    for (int i = 0; i < 4; i++)
        tl[ty + i * 8][tx] = W[(kb + ty + i * 8) * 1024 + nb + tx];
    __syncthreads();
#pragma unroll
    for (int i = 0; i < 4; i++)
        Wt[(nb + ty + i * 8) * 1024 + kb + tx] = f2bf(tl[tx][ty + i * 8] * s);
}

// ---------------- GEMM: C[4096x1024] = A[4096x1024] @ Bt^T (+bias) -------------
// A row-major bf16, Bt: [n][k] bf16.  BM=64 BN=128 BK=64, 4 waves (2Mx2N).
// epi 0: bf16 out [B,H,S,Hd]; epi 1: bf16 out [B,H,Hd,S] (V^T); epi 2: f32 row-major.
__global__ __launch_bounds__(256, 2) void k_gemm(
    const short* __restrict__ A, const short* __restrict__ Bt,
    const float* __restrict__ bias, void* __restrict__ outp,
    float bscale, int epi)
{
    __shared__ alignas(16) short As[64 * 64];
    __shared__ alignas(16) short Bs[128 * 64];
    const int t = threadIdx.x, lane = t & 63;
    const int wv = t >> 6, wr = wv >> 1, wc = wv & 1;
    const int g = lane >> 4, c = lane & 15;
    const int row0 = blockIdx.x * 64, col0 = blockIdx.y * 128;

    const f32x4 z4 = {0.f, 0.f, 0.f, 0.f};
    f32x4 acc[2][4];
#pragma unroll
    for (int m = 0; m < 2; m++)
#pragma unroll
        for (int n = 0; n < 4; n++) acc[m][n] = z4;

    for (int kt = 0; kt < 16; ++kt) {
        const int k0 = kt * 64;
        const short* Ag = A + row0 * 1024 + k0;
        const short* Bg = Bt + col0 * 1024 + k0;
#pragma unroll
        for (int j = 0; j < 2; j++) {
            int idx = j * 256 + t;
            int row = idx >> 3, sp = idx & 7, sl = sp ^ (row & 7);
            gload16(Ag + row * 1024 + sl * 8, As + idx * 8);
        }
#pragma unroll
        for (int j = 0; j < 4; j++) {
            int idx = j * 256 + t;
            int row = idx >> 3, sp = idx & 7, sl = sp ^ (row & 7);
            gload16(Bg + row * 1024 + sl * 8, Bs + idx * 8);
        }
        __syncthreads();

        bfv8 af[2][2], bfr[4][2];
#pragma unroll
        for (int m = 0; m < 2; m++)
#pragma unroll
            for (int ks = 0; ks < 2; ks++)
                af[m][ks] = ldsfrag(As, wr * 32 + m * 16 + c, ks * 4 + g);
#pragma unroll
        for (int n = 0; n < 4; n++)
#pragma unroll
            for (int ks = 0; ks < 2; ks++)
                bfr[n][ks] = ldsfrag(Bs, wc * 64 + n * 16 + c, ks * 4 + g);
#pragma unroll
        for (int m = 0; m < 2; m++)
#pragma unroll
            for (int n = 0; n < 4; n++)
#pragma unroll
                for (int ks = 0; ks < 2; ks++)
                    acc[m][n] = mfma16(af[m][ks], bfr[n][ks], acc[m][n]);
        __syncthreads();
    }

    // epilogue: C row = row0 + wr*32 + m*16 + g*4 + r ; col = col0 + wc*64 + n*16 + c
#pragma unroll
    for (int n = 0; n < 4; n++) {
        const int gc = col0 + wc * 64 + n * 16 + c;
        const float bvl = bias[gc] * bscale;
        const int h = gc >> 6, d = gc & 63;
#pragma unroll
        for (int m = 0; m < 2; m++) {
            const int gr = row0 + wr * 32 + m * 16 + g * 4;
            if (epi == 2) {
                float* O = (float*)outp;
#pragma unroll
                for (int r = 0; r < 4; r++) O[(gr + r) * 1024 + gc] = acc[m][n][r] + bvl;
            } else {
                const int b = gr >> 11, sr = gr & 2047;
                short* O = (short*)outp;
                if (epi == 0) {
                    int base = ((b * 16 + h) * 2048 + sr) * 64 + d;
#pragma unroll
                    for (int r = 0; r < 4; r++) O[base + r * 64] = f2bf(acc[m][n][r] + bvl);
                } else {
                    s4v vv;
#pragma unroll
                    for (int r = 0; r < 4; r++) vv[r] = f2bf(acc[m][n][r] + bvl);
                    *reinterpret_cast<s4v*>(O + ((b * 16 + h) * 64 + d) * 2048 + sr) = vv;
                }
            }
        }
    }
}

// ---------------- flash attention, swapped-operand (S^T / O^T) form ------------
// Q,K: [B,H,S,64] bf16 (Q pre-scaled by 0.125*log2e), Vt: [B,H,64,S] bf16,
// bb: 0.5*log2e*binding bf16 [S,S].  Ob: [B,S,1024] bf16.
// Grid: (S/128, B*H). 4 waves x 32 q-rows. KV tile = 64, double-buffered LDS.
// Softmax runs in exp2 domain; lane (g,c) owns q-row (jq*16+c) stats.
__global__ __launch_bounds__(256, 2) void k_attn(
    const short* __restrict__ Q, const short* __restrict__ K,
    const short* __restrict__ Vt, const short* __restrict__ bb,
    short* __restrict__ Ob)
{
    __shared__ alignas(16) short Ks[2][64 * 64];
    __shared__ alignas(16) short Vs[2][64 * 64];
    __shared__ alignas(16) short Ps[4][32 * 64];
    const int t = threadIdx.x, lane = t & 63;
    const int wv = t >> 6, g = lane >> 4, c = lane & 15;
    const int qt = blockIdx.x, bh = blockIdx.y;
    const int b = bh >> 4, h = bh & 15;
    const short* Qb = Q + bh * 2048 * 64;
    const short* Kb = K + bh * 2048 * 64;
    const short* Vb = Vt + bh * 64 * 2048;
    const int q0 = qt * 128 + wv * 32;

    // Q fragments (second-operand layout): lane holds Q row (q0+jq*16+c)
    bfv8 qf[2][2];
#pragma unroll
    for (int jq = 0; jq < 2; jq++)
#pragma unroll
        for (int ks = 0; ks < 2; ks++)
            qf[jq][ks] = *reinterpret_cast<const bfv8*>(
                Qb + (q0 + jq * 16 + c) * 64 + ks * 32 + g * 8);

    const f32x4 z4 = {0.f, 0.f, 0.f, 0.f};
    f32x4 oa[4][2];          // [nd][jq]; elem r: O^T[d=nd*16+g*4+r][q=jq*16+c]
#pragma unroll
    for (int nd = 0; nd < 4; nd++)
#pragma unroll
        for (int jq = 0; jq < 2; jq++) oa[nd][jq] = z4;
    float mrun[2] = {-3.0e38f, -3.0e38f}, lrun[2] = {0.f, 0.f};

    auto stage = [&](int buf, int kt) {
#pragma unroll
        for (int j = 0; j < 2; j++) {
            int idx = j * 256 + t;
            int row = idx >> 3, sp = idx & 7, sl = sp ^ (row & 7);
            gload16(Kb + (kt * 64 + row) * 64 + sl * 8, &Ks[buf][idx * 8]);
            gload16(Vb + row * 2048 + kt * 64 + sl * 8, &Vs[buf][idx * 8]);
        }
    };
    s4v bn[2][4];  // bias prefetch: bn[jq][n] = bb[q0+jq*16+c][kt*64+n*16+4g .. +3]
    auto ldbias = [&](int kt) {
#pragma unroll
        for (int jq = 0; jq < 2; jq++)
#pragma unroll
            for (int n = 0; n < 4; n++)
                bn[jq][n] = *reinterpret_cast<const s4v*>(
                    bb + (size_t)(q0 + jq * 16 + c) * 2048 + kt * 64 + n * 16 + 4 * g);
    };

    stage(0, 0);
    ldbias(0);
    __syncthreads();

    for (int kt = 0; kt < 32; ++kt) {
        const int cur = kt & 1;
        if (kt < 31) stage(cur ^ 1, kt + 1);
        s4v bc[2][4];
#pragma unroll
        for (int jq = 0; jq < 2; jq++)
#pragma unroll
            for (int n = 0; n < 4; n++) bc[jq][n] = bn[jq][n];
        if (kt < 31) ldbias(kt + 1);

        const short* Kc = &Ks[cur][0];
        const short* Vc = &Vs[cur][0];

        // S^T tile: sc[n][jq], elem r: S[q=jq*16+c][k=n*16+g*4+r] (exp2 domain)
        f32x4 sc[4][2];
#pragma unroll
        for (int n = 0; n < 4; n++) {
            sc[n][0] = z4; sc[n][1] = z4;
            bfv8 k0 = ldsfrag(Kc, n * 16 + c, g);
            bfv8 k1 = ldsfrag(Kc, n * 16 + c, 4 + g);
#pragma unroll
            for (int jq = 0; jq < 2; jq++) {
                sc[n][jq] = mfma16(k0, qf[jq][0], sc[n][jq]);
                sc[n][jq] = mfma16(k1, qf[jq][1], sc[n][jq]);
            }
        }
        // + binding bias (already *0.5*log2e, bf16)
#pragma unroll
        for (int jq = 0; jq < 2; jq++)
#pragma unroll
            for (int n = 0; n < 4; n++)
#pragma unroll
                for (int r = 0; r < 4; r++)
                    sc[n][jq][r] += bf2f(bc[jq][n][r]);

        char* Pb = (char*)&Ps[wv][0];
#pragma unroll
        for (int jq = 0; jq < 2; jq++) {
            // in-lane max over 16, then xor-16/32 across the 4 g-lanes
            float pn[4];
#pragma unroll
            for (int n = 0; n < 4; n++)
                pn[n] = fmaxf(fmaxf(sc[n][jq][0], sc[n][jq][1]),
                              fmaxf(sc[n][jq][2], sc[n][jq][3]));
            float pm = fmaxf(fmaxf(pn[0], pn[1]), fmaxf(pn[2], pn[3]));
            pm = fmaxf(pm, __shfl_xor(pm, 16));
            pm = fmaxf(pm, __shfl_xor(pm, 32));
            const float mn = fmaxf(mrun[jq], pm);
            const float corr = __builtin_amdgcn_exp2f(mrun[jq] - mn);
            mrun[jq] = mn;
            float sn[4];
#pragma unroll
            for (int n = 0; n < 4; n++) {
                float p0 = __builtin_amdgcn_exp2f(sc[n][jq][0] - mn);
                float p1 = __builtin_amdgcn_exp2f(sc[n][jq][1] - mn);
                float p2 = __builtin_amdgcn_exp2f(sc[n][jq][2] - mn);
                float p3 = __builtin_amdgcn_exp2f(sc[n][jq][3] - mn);
                sc[n][jq][0] = p0; sc[n][jq][1] = p1;
                sc[n][jq][2] = p2; sc[n][jq][3] = p3;
                sn[n] = (p0 + p1) + (p2 + p3);
            }
            float rs = (sn[0] + sn[1]) + (sn[2] + sn[3]);
            rs += __shfl_xor(rs, 16);
            rs += __shfl_xor(rs, 32);
            lrun[jq] = lrun[jq] * corr + rs;
#pragma unroll
            for (int nd = 0; nd < 4; nd++)
#pragma unroll
                for (int r = 0; r < 4; r++) oa[nd][jq][r] *= corr;

            // pack P row chunk -> swizzled per-wave LDS tile [32 q][64 k]
            const int row = jq * 16 + c, rx = row & 7;
#pragma unroll
            for (int n = 0; n < 4; n++) {
                unsigned w0, w1;
                asm("v_cvt_pk_bf16_f32 %0, %1, %2" : "=v"(w0)
                    : "v"(sc[n][jq][0]), "v"(sc[n][jq][1]));
                asm("v_cvt_pk_bf16_f32 %0, %1, %2" : "=v"(w1)
                    : "v"(sc[n][jq][2]), "v"(sc[n][jq][3]));
                uint2 wp; wp.x = w0; wp.y = w1;
                *reinterpret_cast<uint2*>(
                    Pb + row * 128 + (((2 * n + (g >> 1)) ^ rx) << 4) + ((g & 1) << 3)) = wp;
            }
        }

        // PV (swapped): oa[nd][jq] += V^T-frag x P-frag
        bfv8 pa[2][2];
#pragma unroll
        for (int jq = 0; jq < 2; jq++) {
            const int row = jq * 16 + c, rx = row & 7;
#pragma unroll
            for (int ks = 0; ks < 2; ks++)
                pa[jq][ks] = *reinterpret_cast<const bfv8*>(
                    Pb + row * 128 + (((4 * ks + g) ^ rx) << 4));
        }
#pragma unroll
        for (int nd = 0; nd < 4; nd++) {
            bfv8 v0 = ldsfrag(Vc, nd * 16 + c, g);
            bfv8 v1 = ldsfrag(Vc, nd * 16 + c, 4 + g);
#pragma unroll
            for (int jq = 0; jq < 2; jq++) {
                oa[nd][jq] = mfma16(v0, pa[jq][0], oa[nd][jq]);
                oa[nd][jq] = mfma16(v1, pa[jq][1], oa[nd][jq]);
            }
        }
        __syncthreads();
    }

    // epilogue: O^T frag -> Ob[B,S,1024], 8B stores
    const float rl0 = 1.f / lrun[0], rl1 = 1.f / lrun[1];
#pragma unroll
    for (int jq = 0; jq < 2; jq++) {
        const float rl = jq ? rl1 : rl0;
        const size_t srow = (size_t)(b * 2048 + q0 + jq * 16 + c);
#pragma unroll
        for (int nd = 0; nd < 4; nd++) {
            s4v st;
#pragma unroll
            for (int r = 0; r < 4; r++) st[r] = f2bf(oa[nd][jq][r] * rl);
            *reinterpret_cast<s4v*>(Ob + srow * 1024 + h * 64 + nd * 16 + 4 * g) = st;
        }
    }
}

extern "C" void kernel_launch(void* const* d_in, const int* in_sizes, int n_in,
                              void* d_out, int out_size, void* d_ws, size_t ws_size,
                              hipStream_t stream)
{
    (void)in_sizes; (void)n_in; (void)out_size; (void)ws_size;
    const float* x    = (const float*)d_in[0];
    const float* bind = (const float*)d_in[1];
    const float* Wq   = (const float*)d_in[2];
    const float* bq   = (const float*)d_in[3];
    const float* Wk   = (const float*)d_in[4];
    const float* bk   = (const float*)d_in[5];
    const float* Wv   = (const float*)d_in[6];
    const float* bv   = (const float*)d_in[7];
    const float* Wo   = (const float*)d_in[8];
    const float* bo   = (const float*)d_in[9];

    char* ws = (char*)d_ws;
    const size_t MB = (size_t)1 << 20;
    short* xb   = (short*)(ws + 0 * MB);   // 8 MiB  x as bf16
    short* Wqt  = (short*)(ws + 8 * MB);   // 2 MiB  each, [n][k] bf16
    short* Wkt  = (short*)(ws + 10 * MB);
    short* Wvt  = (short*)(ws + 12 * MB);
    short* Wot  = (short*)(ws + 14 * MB);
    short* bbm  = (short*)(ws + 16 * MB);  // 8 MiB  0.5*log2e*binding bf16
    short* Qs   = (short*)(ws + 24 * MB);  // 8 MiB  [B,H,S,64]
    short* Kst  = (short*)(ws + 32 * MB);  // 8 MiB  [B,H,S,64]
    short* Vts  = (short*)(ws + 40 * MB);  // 8 MiB  [B,H,64,S]
    short* Obuf = (short*)(ws + 48 * MB);  // 8 MiB  [B,S,1024]

    const float LOG2E = 1.4426950408889634f;
    const float SCQ = 0.125f * LOG2E;   // hd^-0.5 * log2e, folded into Wq/bq
    const float SCB = 0.5f * LOG2E;     // binding_bias * log2e

    k_cvt<<<2048, 256, 0, stream>>>(x, xb, 1.f);
    k_cvt<<<2048, 256, 0, stream>>>(bind, bbm, SCB);
    k_transpose<<<dim3(32, 32), 256, 0, stream>>>(Wq, Wqt, SCQ);
    k_transpose<<<dim3(32, 32), 256, 0, stream>>>(Wk, Wkt, 1.f);
    k_transpose<<<dim3(32, 32), 256, 0, stream>>>(Wv, Wvt, 1.f);
    k_transpose<<<dim3(32, 32), 256, 0, stream>>>(Wo, Wot, 1.f);
    k_gemm<<<dim3(64, 8), 256, 0, stream>>>(xb, Wqt, bq, Qs, SCQ, 0);
    k_gemm<<<dim3(64, 8), 256, 0, stream>>>(xb, Wkt, bk, Kst, 1.f, 0);
    k_gemm<<<dim3(64, 8), 256, 0, stream>>>(xb, Wvt, bv, Vts, 1.f, 1);
    k_attn<<<dim3(16, 32), 256, 0, stream>>>(Qs, Kst, Vts, bbm, Obuf);
    k_gemm<<<dim3(64, 8), 256, 0, stream>>>(Obuf, Wot, bo, d_out, 1.f, 2);
}

// Round 3
// 169.422 us; speedup vs baseline: 1.2209x; 1.0403x over previous
//
#include <hip/hip_runtime.h>

#define DEV static __device__ __forceinline__

typedef __attribute__((ext_vector_type(4))) float f32x4;
typedef __attribute__((ext_vector_type(8))) __bf16 bfv8;
typedef __attribute__((ext_vector_type(8))) short s8v;
typedef __attribute__((ext_vector_type(4))) short s4v;

DEV short f2bf(float f) {
    unsigned u = __float_as_uint(f);
    u = (u + 0x7fffu + ((u >> 16) & 1u)) >> 16;
    return (short)u;
}
DEV float bf2f(short s) { return __uint_as_float(((unsigned)(unsigned short)s) << 16); }

DEV void gload16(const void* g, void* l) {
    __builtin_amdgcn_global_load_lds(
        (const __attribute__((address_space(1))) void*)g,
        (__attribute__((address_space(3))) void*)l, 16, 0, 0);
}

DEV f32x4 mfma16(bfv8 a, bfv8 b, f32x4 c) {
    return __builtin_amdgcn_mfma_f32_16x16x32_bf16(a, b, c, 0, 0, 0);
}

// LDS tile layout: [row][8 slots of 8 bf16], physical slot = logical slot ^ (row&7)
DEV bfv8 ldsfrag(const short* base, int row, int slog) {
    int sp = slog ^ (row & 7);
    return *reinterpret_cast<const bfv8*>(base + row * 64 + sp * 8);
}

// ---------------- f32 -> bf16 elementwise (8 elems/thread, exact-fit grid) ----
__global__ void k_cvt(const float* __restrict__ in, short* __restrict__ out, float s) {
    int i = blockIdx.x * blockDim.x + threadIdx.x;
    const float4* p = (const float4*)in + (size_t)i * 2;
    float4 a = p[0], b = p[1];
    s8v o;
    o[0] = f2bf(a.x * s); o[1] = f2bf(a.y * s); o[2] = f2bf(a.z * s); o[3] = f2bf(a.w * s);
    o[4] = f2bf(b.x * s); o[5] = f2bf(b.y * s); o[6] = f2bf(b.z * s); o[7] = f2bf(b.w * s);
    reinterpret_cast<s8v*>(out)[i] = o;
}

// ---------------- W [1024x1024] f32 (k-major) -> Wt [n][k] bf16 ----------------
__global__ void k_transpose(const float* __restrict__ W, short* __restrict__ Wt, float s) {
    __shared__ float tl[32][33];
    int tx = threadIdx.x & 31, ty = threadIdx.x >> 5;
    int nb = blockIdx.x * 32, kb = blockIdx.y * 32;
#pragma unroll
    for (int i = 0; i < 4; i++)
        tl[ty + i * 8][tx] = W[(kb + ty + i * 8) * 1024 + nb + tx];
    __syncthreads();
#pragma unroll
    for (int i = 0; i < 4; i++)
        Wt[(nb + ty + i * 8) * 1024 + kb + tx] = f2bf(tl[tx][ty + i * 8] * s);
}

// ---------------- GEMM: C[4096x1024] = A[4096x1024] @ Bt^T (+bias) -------------
// A row-major bf16, Bt: [n][k] bf16.  BM=64 BN=128 BK=64, 4 waves (2Mx2N).
// epi 0: bf16 out [B,H,S,Hd]; epi 1: bf16 out [B,H,Hd,S] (V^T); epi 2: f32 row-major.
__global__ __launch_bounds__(256, 2) void k_gemm(
    const short* __restrict__ A, const short* __restrict__ Bt,
    const float* __restrict__ bias, void* __restrict__ outp,
    float bscale, int epi)
{
    __shared__ alignas(16) short As[64 * 64];
    __shared__ alignas(16) short Bs[128 * 64];
    const int t = threadIdx.x, lane = t & 63;
    const int wv = t >> 6, wr = wv >> 1, wc = wv & 1;
    const int g = lane >> 4, c = lane & 15;
    const int row0 = blockIdx.x * 64, col0 = blockIdx.y * 128;

    const f32x4 z4 = {0.f, 0.f, 0.f, 0.f};
    f32x4 acc[2][4];
#pragma unroll
    for (int m = 0; m < 2; m++)
#pragma unroll
        for (int n = 0; n < 4; n++) acc[m][n] = z4;

    for (int kt = 0; kt < 16; ++kt) {
        const int k0 = kt * 64;
        const short* Ag = A + row0 * 1024 + k0;
        const short* Bg = Bt + col0 * 1024 + k0;
#pragma unroll
        for (int j = 0; j < 2; j++) {
            int idx = j * 256 + t;
            int row = idx >> 3, sp = idx & 7, sl = sp ^ (row & 7);
            gload16(Ag + row * 1024 + sl * 8, As + idx * 8);
        }
#pragma unroll
        for (int j = 0; j < 4; j++) {
            int idx = j * 256 + t;
            int row = idx >> 3, sp = idx & 7, sl = sp ^ (row & 7);
            gload16(Bg + row * 1024 + sl * 8, Bs + idx * 8);
        }
        __syncthreads();

        bfv8 af[2][2], bfr[4][2];
#pragma unroll
        for (int m = 0; m < 2; m++)
#pragma unroll
            for (int ks = 0; ks < 2; ks++)
                af[m][ks] = ldsfrag(As, wr * 32 + m * 16 + c, ks * 4 + g);
#pragma unroll
        for (int n = 0; n < 4; n++)
#pragma unroll
            for (int ks = 0; ks < 2; ks++)
                bfr[n][ks] = ldsfrag(Bs, wc * 64 + n * 16 + c, ks * 4 + g);
#pragma unroll
        for (int m = 0; m < 2; m++)
#pragma unroll
            for (int n = 0; n < 4; n++)
#pragma unroll
                for (int ks = 0; ks < 2; ks++)
                    acc[m][n] = mfma16(af[m][ks], bfr[n][ks], acc[m][n]);
        __syncthreads();
    }

    // epilogue: C row = row0 + wr*32 + m*16 + g*4 + r ; col = col0 + wc*64 + n*16 + c
#pragma unroll
    for (int n = 0; n < 4; n++) {
        const int gc = col0 + wc * 64 + n * 16 + c;
        const float bvl = bias[gc] * bscale;
        const int h = gc >> 6, d = gc & 63;
#pragma unroll
        for (int m = 0; m < 2; m++) {
            const int gr = row0 + wr * 32 + m * 16 + g * 4;
            if (epi == 2) {
                float* O = (float*)outp;
#pragma unroll
                for (int r = 0; r < 4; r++) O[(gr + r) * 1024 + gc] = acc[m][n][r] + bvl;
            } else {
                const int b = gr >> 11, sr = gr & 2047;
                short* O = (short*)outp;
                if (epi == 0) {
                    int base = ((b * 16 + h) * 2048 + sr) * 64 + d;
#pragma unroll
                    for (int r = 0; r < 4; r++) O[base + r * 64] = f2bf(acc[m][n][r] + bvl);
                } else {
                    s4v vv;
#pragma unroll
                    for (int r = 0; r < 4; r++) vv[r] = f2bf(acc[m][n][r] + bvl);
                    *reinterpret_cast<s4v*>(O + ((b * 16 + h) * 64 + d) * 2048 + sr) = vv;
                }
            }
        }
    }
}

// ---------------- flash attention, swapped-operand (S^T / O^T) form ------------
// Q,K: [B,H,S,64] bf16 (Q pre-scaled by 0.125*log2e), Vt: [B,H,64,S] bf16,
// bb: 0.5*log2e*binding bf16 [S,S].  Ob: [B,S,1024] bf16.
// Grid: (S/64, B*H) = 1024 blocks. 4 waves x 16 q-rows. KV tile = 64, dbuf LDS.
// LDS 40KB -> 4 blocks/CU. Softmax in exp2 domain; lane (g,c) owns q-row q0+c.
__global__ __launch_bounds__(256, 4) void k_attn(
    const short* __restrict__ Q, const short* __restrict__ K,
    const short* __restrict__ Vt, const short* __restrict__ bb,
    short* __restrict__ Ob)
{
    __shared__ alignas(16) short Ks[2][64 * 64];
    __shared__ alignas(16) short Vs[2][64 * 64];
    __shared__ alignas(16) short Ps[4][16 * 64];
    const int t = threadIdx.x, lane = t & 63;
    const int wv = t >> 6, g = lane >> 4, c = lane & 15;
    const int qt = blockIdx.x, bh = blockIdx.y;
    const int b = bh >> 4, h = bh & 15;
    const short* Qb = Q + bh * 2048 * 64;
    const short* Kb = K + bh * 2048 * 64;
    const short* Vb = Vt + bh * 64 * 2048;
    const int q0 = qt * 64 + wv * 16;

    // Q fragments (second-operand layout): lane holds Q row (q0+c)
    bfv8 qf[2];
#pragma unroll
    for (int ks = 0; ks < 2; ks++)
        qf[ks] = *reinterpret_cast<const bfv8*>(Qb + (q0 + c) * 64 + ks * 32 + g * 8);

    const f32x4 z4 = {0.f, 0.f, 0.f, 0.f};
    f32x4 oa[4];             // [nd]; elem r: O^T[d=nd*16+g*4+r][q=q0+c]
#pragma unroll
    for (int nd = 0; nd < 4; nd++) oa[nd] = z4;
    float mrun = -3.0e38f, lrun = 0.f;

    auto stage = [&](int buf, int kt) {
#pragma unroll
        for (int j = 0; j < 2; j++) {
            int idx = j * 256 + t;
            int row = idx >> 3, sp = idx & 7, sl = sp ^ (row & 7);
            gload16(Kb + (kt * 64 + row) * 64 + sl * 8, &Ks[buf][idx * 8]);
            gload16(Vb + row * 2048 + kt * 64 + sl * 8, &Vs[buf][idx * 8]);
        }
    };
    s4v bn[4];  // bias prefetch: bn[n] = bb[q0+c][kt*64+n*16+4g .. +3]
    auto ldbias = [&](int kt) {
#pragma unroll
        for (int n = 0; n < 4; n++)
            bn[n] = *reinterpret_cast<const s4v*>(
                bb + (size_t)(q0 + c) * 2048 + kt * 64 + n * 16 + 4 * g);
    };

    stage(0, 0);
    ldbias(0);
    __syncthreads();

    for (int kt = 0; kt < 32; ++kt) {
        const int cur = kt & 1;
        if (kt < 31) stage(cur ^ 1, kt + 1);
        s4v bc[4];
#pragma unroll
        for (int n = 0; n < 4; n++) bc[n] = bn[n];
        if (kt < 31) ldbias(kt + 1);

        const short* Kc = &Ks[cur][0];
        const short* Vc = &Vs[cur][0];

        // S^T tile: sc[n], elem r: S[q=q0+c][k=kt*64+n*16+g*4+r] (exp2 domain)
        f32x4 sc[4];
        __builtin_amdgcn_s_setprio(1);
#pragma unroll
        for (int n = 0; n < 4; n++) {
            sc[n] = z4;
            bfv8 k0 = ldsfrag(Kc, n * 16 + c, g);
            bfv8 k1 = ldsfrag(Kc, n * 16 + c, 4 + g);
            sc[n] = mfma16(k0, qf[0], sc[n]);
            sc[n] = mfma16(k1, qf[1], sc[n]);
        }
        __builtin_amdgcn_s_setprio(0);

        // + binding bias (already *0.5*log2e, bf16)
#pragma unroll
        for (int n = 0; n < 4; n++)
#pragma unroll
            for (int r = 0; r < 4; r++)
                sc[n][r] += bf2f(bc[n][r]);

        // online softmax: in-lane max over 16, xor-16/32 across the 4 g-lanes
        float pn[4];
#pragma unroll
        for (int n = 0; n < 4; n++)
            pn[n] = fmaxf(fmaxf(sc[n][0], sc[n][1]), fmaxf(sc[n][2], sc[n][3]));
        float pm = fmaxf(fmaxf(pn[0], pn[1]), fmaxf(pn[2], pn[3]));
        pm = fmaxf(pm, __shfl_xor(pm, 16));
        pm = fmaxf(pm, __shfl_xor(pm, 32));
        // defer-max (T13): skip rescale while tile max stays within 11.5 (=8*log2e)
        if (!__all(pm <= mrun + 11.5f)) {
            const float mn = fmaxf(mrun, pm);
            const float corr = __builtin_amdgcn_exp2f(mrun - mn);
            mrun = mn;
            lrun *= corr;
#pragma unroll
            for (int nd = 0; nd < 4; nd++)
#pragma unroll
                for (int r = 0; r < 4; r++) oa[nd][r] *= corr;
        }
        float sn[4];
#pragma unroll
        for (int n = 0; n < 4; n++) {
            float p0 = __builtin_amdgcn_exp2f(sc[n][0] - mrun);
            float p1 = __builtin_amdgcn_exp2f(sc[n][1] - mrun);
            float p2 = __builtin_amdgcn_exp2f(sc[n][2] - mrun);
            float p3 = __builtin_amdgcn_exp2f(sc[n][3] - mrun);
            sc[n][0] = p0; sc[n][1] = p1; sc[n][2] = p2; sc[n][3] = p3;
            sn[n] = (p0 + p1) + (p2 + p3);
        }
        float rs = (sn[0] + sn[1]) + (sn[2] + sn[3]);
        rs += __shfl_xor(rs, 16);
        rs += __shfl_xor(rs, 32);
        lrun += rs;

        // pack P row chunk -> swizzled per-wave LDS tile [16 q][64 k]
        char* Pb = (char*)&Ps[wv][0];
        const int rx = c & 7;
#pragma unroll
        for (int n = 0; n < 4; n++) {
            unsigned w0, w1;
            asm("v_cvt_pk_bf16_f32 %0, %1, %2" : "=v"(w0) : "v"(sc[n][0]), "v"(sc[n][1]));
            asm("v_cvt_pk_bf16_f32 %0, %1, %2" : "=v"(w1) : "v"(sc[n][2]), "v"(sc[n][3]));
            uint2 wp; wp.x = w0; wp.y = w1;
            *reinterpret_cast<uint2*>(
                Pb + c * 128 + (((2 * n + (g >> 1)) ^ rx) << 4) + ((g & 1) << 3)) = wp;
        }

        // PV (swapped): oa[nd] += V^T-frag x P-frag
        bfv8 pa[2];
#pragma unroll
        for (int ks = 0; ks < 2; ks++)
            pa[ks] = *reinterpret_cast<const bfv8*>(Pb + c * 128 + (((4 * ks + g) ^ rx) << 4));
        __builtin_amdgcn_s_setprio(1);
#pragma unroll
        for (int nd = 0; nd < 4; nd++) {
            bfv8 v0 = ldsfrag(Vc, nd * 16 + c, g);
            bfv8 v1 = ldsfrag(Vc, nd * 16 + c, 4 + g);
            oa[nd] = mfma16(v0, pa[0], oa[nd]);
            oa[nd] = mfma16(v1, pa[1], oa[nd]);
        }
        __builtin_amdgcn_s_setprio(0);
        __syncthreads();
    }

    // epilogue: O^T frag -> Ob[B,S,1024], 8B stores
    const float rl = 1.f / lrun;
    const size_t srow = (size_t)(b * 2048 + q0 + c);
#pragma unroll
    for (int nd = 0; nd < 4; nd++) {
        s4v st;
#pragma unroll
        for (int r = 0; r < 4; r++) st[r] = f2bf(oa[nd][r] * rl);
        *reinterpret_cast<s4v*>(Ob + srow * 1024 + h * 64 + nd * 16 + 4 * g) = st;
    }
}

extern "C" void kernel_launch(void* const* d_in, const int* in_sizes, int n_in,
                              void* d_out, int out_size, void* d_ws, size_t ws_size,
                              hipStream_t stream)
{
    (void)in_sizes; (void)n_in; (void)out_size; (void)ws_size;
    const float* x    = (const float*)d_in[0];
    const float* bind = (const float*)d_in[1];
    const float* Wq   = (const float*)d_in[2];
    const float* bq   = (const float*)d_in[3];
    const float* Wk   = (const float*)d_in[4];
    const float* bk   = (const float*)d_in[5];
    const float* Wv   = (const float*)d_in[6];
    const float* bv   = (const float*)d_in[7];
    const float* Wo   = (const float*)d_in[8];
    const float* bo   = (const float*)d_in[9];

    char* ws = (char*)d_ws;
    const size_t MB = (size_t)1 << 20;
    short* xb   = (short*)(ws + 0 * MB);   // 8 MiB  x as bf16
    short* Wqt  = (short*)(ws + 8 * MB);   // 2 MiB  each, [n][k] bf16
    short* Wkt  = (short*)(ws + 10 * MB);
    short* Wvt  = (short*)(ws + 12 * MB);
    short* Wot  = (short*)(ws + 14 * MB);
    short* bbm  = (short*)(ws + 16 * MB);  // 8 MiB  0.5*log2e*binding bf16
    short* Qs   = (short*)(ws + 24 * MB);  // 8 MiB  [B,H,S,64]
    short* Kst  = (short*)(ws + 32 * MB);  // 8 MiB  [B,H,S,64]
    short* Vts  = (short*)(ws + 40 * MB);  // 8 MiB  [B,H,64,S]
    short* Obuf = (short*)(ws + 48 * MB);  // 8 MiB  [B,S,1024]

    const float LOG2E = 1.4426950408889634f;
    const float SCQ = 0.125f * LOG2E;   // hd^-0.5 * log2e, folded into Wq/bq
    const float SCB = 0.5f * LOG2E;     // binding_bias * log2e

    k_cvt<<<2048, 256, 0, stream>>>(x, xb, 1.f);
    k_cvt<<<2048, 256, 0, stream>>>(bind, bbm, SCB);
    k_transpose<<<dim3(32, 32), 256, 0, stream>>>(Wq, Wqt, SCQ);
    k_transpose<<<dim3(32, 32), 256, 0, stream>>>(Wk, Wkt, 1.f);
    k_transpose<<<dim3(32, 32), 256, 0, stream>>>(Wv, Wvt, 1.f);
    k_transpose<<<dim3(32, 32), 256, 0, stream>>>(Wo, Wot, 1.f);
    k_gemm<<<dim3(64, 8), 256, 0, stream>>>(xb, Wqt, bq, Qs, SCQ, 0);
    k_gemm<<<dim3(64, 8), 256, 0, stream>>>(xb, Wkt, bk, Kst, 1.f, 0);
    k_gemm<<<dim3(64, 8), 256, 0, stream>>>(xb, Wvt, bv, Vts, 1.f, 1);
    k_attn<<<dim3(32, 32), 256, 0, stream>>>(Qs, Kst, Vts, bbm, Obuf);
    k_gemm<<<dim3(64, 8), 256, 0, stream>>>(Obuf, Wot, bo, d_out, 1.f, 2);
}

// Round 4
// 146.696 us; speedup vs baseline: 1.4100x; 1.1549x over previous
//
#include <hip/hip_runtime.h>

#define DEV static __device__ __forceinline__

typedef __attribute__((ext_vector_type(4))) float f32x4;
typedef __attribute__((ext_vector_type(8))) __bf16 bfv8;
typedef __attribute__((ext_vector_type(8))) short s8v;
typedef __attribute__((ext_vector_type(4))) short s4v;

DEV short f2bf(float f) {
    unsigned u = __float_as_uint(f);
    u = (u + 0x7fffu + ((u >> 16) & 1u)) >> 16;
    return (short)u;
}
DEV float bf2f(short s) { return __uint_as_float(((unsigned)(unsigned short)s) << 16); }

DEV void gload16(const void* g, void* l) {
    __builtin_amdgcn_global_load_lds(
        (const __attribute__((address_space(1))) void*)g,
        (__attribute__((address_space(3))) void*)l, 16, 0, 0);
}

DEV f32x4 mfma16(bfv8 a, bfv8 b, f32x4 c) {
    return __builtin_amdgcn_mfma_f32_16x16x32_bf16(a, b, c, 0, 0, 0);
}

DEV float max3f(float a, float b, float c) {
    float d;
    asm("v_max3_f32 %0, %1, %2, %3" : "=v"(d) : "v"(a), "v"(b), "v"(c));
    return d;
}

// LDS tile layout: [row][8 slots of 8 bf16], physical slot = logical slot ^ (row&7)
DEV bfv8 ldsfrag(const short* base, int row, int slog) {
    int sp = slog ^ (row & 7);
    return *reinterpret_cast<const bfv8*>(base + row * 64 + sp * 8);
}

// ---------------- f32 -> bf16 elementwise (8 elems/thread, exact-fit grid) ----
__global__ void k_cvt(const float* __restrict__ in, short* __restrict__ out, float s) {
    int i = blockIdx.x * blockDim.x + threadIdx.x;
    const float4* p = (const float4*)in + (size_t)i * 2;
    float4 a = p[0], b = p[1];
    s8v o;
    o[0] = f2bf(a.x * s); o[1] = f2bf(a.y * s); o[2] = f2bf(a.z * s); o[3] = f2bf(a.w * s);
    o[4] = f2bf(b.x * s); o[5] = f2bf(b.y * s); o[6] = f2bf(b.z * s); o[7] = f2bf(b.w * s);
    reinterpret_cast<s8v*>(out)[i] = o;
}

// ---------------- all four W [1024x1024] f32 -> Wt [n][k] bf16 (z selects) -----
__global__ void k_transpose4(
    const float* __restrict__ W0, const float* __restrict__ W1,
    const float* __restrict__ W2, const float* __restrict__ W3,
    short* __restrict__ T0, short* __restrict__ T1,
    short* __restrict__ T2, short* __restrict__ T3, float s0)
{
    __shared__ float tl[32][33];
    const int z = blockIdx.z;
    const float* W = z == 0 ? W0 : z == 1 ? W1 : z == 2 ? W2 : W3;
    short* Wt = z == 0 ? T0 : z == 1 ? T1 : z == 2 ? T2 : T3;
    const float s = z == 0 ? s0 : 1.f;
    int tx = threadIdx.x & 31, ty = threadIdx.x >> 5;
    int nb = blockIdx.x * 32, kb = blockIdx.y * 32;
#pragma unroll
    for (int i = 0; i < 4; i++)
        tl[ty + i * 8][tx] = W[(kb + ty + i * 8) * 1024 + nb + tx];
    __syncthreads();
#pragma unroll
    for (int i = 0; i < 4; i++)
        Wt[(nb + ty + i * 8) * 1024 + kb + tx] = f2bf(tl[tx][ty + i * 8] * s);
}

// ---------------- GEMM core (BM=64 BN=128 BK=64, 4 waves 2Mx2N) ---------------
// epi 0: bf16 out [B,H,S,Hd]; epi 1: bf16 out [B,H,Hd,S] (V^T); epi 2: f32 row-major.
template <int EPI>
DEV void gemm_body(const short* __restrict__ A, const short* __restrict__ Bt,
                   const float* __restrict__ bias, void* __restrict__ outp,
                   float bscale, int row0, int col0, short* As, short* Bs)
{
    const int t = threadIdx.x, lane = t & 63;
    const int wv = t >> 6, wr = wv >> 1, wc = wv & 1;
    const int g = lane >> 4, c = lane & 15;

    const f32x4 z4 = {0.f, 0.f, 0.f, 0.f};
    f32x4 acc[2][4];
#pragma unroll
    for (int m = 0; m < 2; m++)
#pragma unroll
        for (int n = 0; n < 4; n++) acc[m][n] = z4;

    for (int kt = 0; kt < 16; ++kt) {
        const int k0 = kt * 64;
        const short* Ag = A + row0 * 1024 + k0;
        const short* Bg = Bt + col0 * 1024 + k0;
#pragma unroll
        for (int j = 0; j < 2; j++) {
            int idx = j * 256 + t;
            int row = idx >> 3, sp = idx & 7, sl = sp ^ (row & 7);
            gload16(Ag + row * 1024 + sl * 8, As + idx * 8);
        }
#pragma unroll
        for (int j = 0; j < 4; j++) {
            int idx = j * 256 + t;
            int row = idx >> 3, sp = idx & 7, sl = sp ^ (row & 7);
            gload16(Bg + row * 1024 + sl * 8, Bs + idx * 8);
        }
        __syncthreads();

        bfv8 af[2][2], bfr[4][2];
#pragma unroll
        for (int m = 0; m < 2; m++)
#pragma unroll
            for (int ks = 0; ks < 2; ks++)
                af[m][ks] = ldsfrag(As, wr * 32 + m * 16 + c, ks * 4 + g);
#pragma unroll
        for (int n = 0; n < 4; n++)
#pragma unroll
            for (int ks = 0; ks < 2; ks++)
                bfr[n][ks] = ldsfrag(Bs, wc * 64 + n * 16 + c, ks * 4 + g);
        __builtin_amdgcn_s_setprio(1);
#pragma unroll
        for (int m = 0; m < 2; m++)
#pragma unroll
            for (int n = 0; n < 4; n++)
#pragma unroll
                for (int ks = 0; ks < 2; ks++)
                    acc[m][n] = mfma16(af[m][ks], bfr[n][ks], acc[m][n]);
        __builtin_amdgcn_s_setprio(0);
        __syncthreads();
    }

    // epilogue: C row = row0 + wr*32 + m*16 + g*4 + r ; col = col0 + wc*64 + n*16 + c
#pragma unroll
    for (int n = 0; n < 4; n++) {
        const int gc = col0 + wc * 64 + n * 16 + c;
        const float bvl = bias[gc] * bscale;
        const int h = gc >> 6, d = gc & 63;
#pragma unroll
        for (int m = 0; m < 2; m++) {
            const int gr = row0 + wr * 32 + m * 16 + g * 4;
            if (EPI == 2) {
                float* O = (float*)outp;
#pragma unroll
                for (int r = 0; r < 4; r++) O[(gr + r) * 1024 + gc] = acc[m][n][r] + bvl;
            } else {
                const int b = gr >> 11, sr = gr & 2047;
                short* O = (short*)outp;
                if (EPI == 0) {
                    int base = ((b * 16 + h) * 2048 + sr) * 64 + d;
#pragma unroll
                    for (int r = 0; r < 4; r++) O[base + r * 64] = f2bf(acc[m][n][r] + bvl);
                } else {
                    s4v vv;
#pragma unroll
                    for (int r = 0; r < 4; r++) vv[r] = f2bf(acc[m][n][r] + bvl);
                    *reinterpret_cast<s4v*>(O + ((b * 16 + h) * 64 + d) * 2048 + sr) = vv;
                }
            }
        }
    }
}

// fused QKV projection: grid (64, 24); y/8 selects Q/K/V
__global__ __launch_bounds__(256, 2) void k_gemm3(
    const short* __restrict__ A,
    const short* __restrict__ WqT, const short* __restrict__ WkT, const short* __restrict__ WvT,
    const float* __restrict__ bq, const float* __restrict__ bk, const float* __restrict__ bv,
    short* __restrict__ Qs, short* __restrict__ Kst, short* __restrict__ Vts, float scq)
{
    __shared__ alignas(16) short As[64 * 64];
    __shared__ alignas(16) short Bs[128 * 64];
    const int which = blockIdx.y >> 3;
    const int col0 = (blockIdx.y & 7) * 128;
    const int row0 = blockIdx.x * 64;
    if (which == 0)
        gemm_body<0>(A, WqT, bq, Qs, scq, row0, col0, As, Bs);
    else if (which == 1)
        gemm_body<0>(A, WkT, bk, Kst, 1.f, row0, col0, As, Bs);
    else
        gemm_body<1>(A, WvT, bv, Vts, 1.f, row0, col0, As, Bs);
}

// final projection
__global__ __launch_bounds__(256, 2) void k_gemmO(
    const short* __restrict__ A, const short* __restrict__ Bt,
    const float* __restrict__ bias, float* __restrict__ outp)
{
    __shared__ alignas(16) short As[64 * 64];
    __shared__ alignas(16) short Bs[128 * 64];
    gemm_body<2>(A, Bt, bias, outp, 1.f, blockIdx.x * 64, blockIdx.y * 128, As, Bs);
}

// ---------------- flash attention, swapped-operand (S^T / O^T) form ------------
// Q,K: [B,H,S,64] bf16 (Q pre-scaled by 0.125*log2e), Vt: [B,H,64,S] bf16,
// bb: 0.5*log2e*binding bf16 [S,S].  Ob: [B,S,1024] bf16.
// Grid: (S/64, B*H) = 1024 blocks. 4 waves x 16 q-rows. KV tile = 64, dbuf LDS.
// Softmax in exp2 domain with fixed max-estimate MEST (=20, > any logit);
// online-rescale kept as a post-PV correction (corr multiplies oa & lrun equally).
// Bias enters as the QK^T MFMA accumulator init (zero VALU adds).
__global__ __launch_bounds__(256, 4) void k_attn(
    const short* __restrict__ Q, const short* __restrict__ K,
    const short* __restrict__ Vt, const short* __restrict__ bb,
    short* __restrict__ Ob)
{
    __shared__ alignas(16) short Ks[2][64 * 64];
    __shared__ alignas(16) short Vs[2][64 * 64];
    __shared__ alignas(16) short Ps[4][16 * 64];
    const int t = threadIdx.x, lane = t & 63;
    const int wv = t >> 6, g = lane >> 4, c = lane & 15;
    const int qt = blockIdx.x, bh = blockIdx.y;
    const int b = bh >> 4, h = bh & 15;
    const short* Qb = Q + bh * 2048 * 64;
    const short* Kb = K + bh * 2048 * 64;
    const short* Vb = Vt + bh * 64 * 2048;
    const int q0 = qt * 64 + wv * 16;

    // Q fragments (second-operand layout): lane holds Q row (q0+c)
    bfv8 qf[2];
#pragma unroll
    for (int ks = 0; ks < 2; ks++)
        qf[ks] = *reinterpret_cast<const bfv8*>(Qb + (q0 + c) * 64 + ks * 32 + g * 8);

    const f32x4 z4 = {0.f, 0.f, 0.f, 0.f};
    f32x4 oa[4];             // [nd]; elem r: O^T[d=nd*16+g*4+r][q=q0+c]
#pragma unroll
    for (int nd = 0; nd < 4; nd++) oa[nd] = z4;
    float mrun = 20.0f, lrun = 0.f;   // MEST: logits bounded ~|12|

    // staging pointers (strength-reduced)
    const int idx0 = t, idx1 = 256 + t;
    const int r0 = idx0 >> 3, s0 = ((idx0 & 7) ^ (r0 & 7)) * 8;
    const int r1 = idx1 >> 3, s1 = ((idx1 & 7) ^ (r1 & 7)) * 8;
    const short* kp0 = Kb + r0 * 64 + s0;
    const short* kp1 = Kb + r1 * 64 + s1;
    const short* vp0 = Vb + r0 * 2048 + s0;
    const short* vp1 = Vb + r1 * 2048 + s1;
    const short* bbp = bb + (size_t)(q0 + c) * 2048 + 4 * g;

    // hoisted P-tile LDS addresses
    char* Pb = (char*)&Ps[wv][0];
    const int rx = c & 7;
    char* pw[4];
#pragma unroll
    for (int n = 0; n < 4; n++)
        pw[n] = Pb + c * 128 + (((2 * n + (g >> 1)) ^ rx) << 4) + ((g & 1) << 3);
    const char* pr0 = Pb + c * 128 + ((g ^ rx) << 4);
    const char* pr1 = Pb + c * 128 + (((4 + g) ^ rx) << 4);

    // initial stage + bias prefetch
    gload16(kp0, &Ks[0][idx0 * 8]);
    gload16(kp1, &Ks[0][idx1 * 8]);
    gload16(vp0, &Vs[0][idx0 * 8]);
    gload16(vp1, &Vs[0][idx1 * 8]);
    kp0 += 4096; kp1 += 4096; vp0 += 64; vp1 += 64;
    s4v bn[4];
#pragma unroll
    for (int n = 0; n < 4; n++) bn[n] = *reinterpret_cast<const s4v*>(bbp + n * 16);
    bbp += 64;
    __syncthreads();

    for (int kt = 0; kt < 32; ++kt) {
        const int cur = kt & 1;
        // consume bias prefetch -> f32 C-init fragments
        f32x4 cb[4];
#pragma unroll
        for (int n = 0; n < 4; n++)
#pragma unroll
            for (int r = 0; r < 4; r++) cb[n][r] = bf2f(bn[n][r]);
        if (kt < 31) {
            const int nb = cur ^ 1;
            gload16(kp0, &Ks[nb][idx0 * 8]);
            gload16(kp1, &Ks[nb][idx1 * 8]);
            gload16(vp0, &Vs[nb][idx0 * 8]);
            gload16(vp1, &Vs[nb][idx1 * 8]);
            kp0 += 4096; kp1 += 4096; vp0 += 64; vp1 += 64;
#pragma unroll
            for (int n = 0; n < 4; n++) bn[n] = *reinterpret_cast<const s4v*>(bbp + n * 16);
            bbp += 64;
        }

        const short* Kc = &Ks[cur][0];
        const short* Vc = &Vs[cur][0];

        // S^T tile with bias as accumulator init: sc[n][r] = bias + QK
        f32x4 sc[4];
        __builtin_amdgcn_s_setprio(1);
#pragma unroll
        for (int n = 0; n < 4; n++) {
            bfv8 k0 = ldsfrag(Kc, n * 16 + c, g);
            bfv8 k1 = ldsfrag(Kc, n * 16 + c, 4 + g);
            sc[n] = mfma16(k0, qf[0], cb[n]);
            sc[n] = mfma16(k1, qf[1], sc[n]);
        }
        __builtin_amdgcn_s_setprio(0);

        // speculative exp2 against running max-estimate (no branch wait)
#pragma unroll
        for (int n = 0; n < 4; n++)
#pragma unroll
            for (int r = 0; r < 4; r++)
                sc[n][r] = __builtin_amdgcn_exp2f(sc[n][r] - mrun);

        // pack P -> swizzled per-wave LDS tile [16 q][64 k]
#pragma unroll
        for (int n = 0; n < 4; n++) {
            unsigned w0, w1;
            asm("v_cvt_pk_bf16_f32 %0, %1, %2" : "=v"(w0) : "v"(sc[n][0]), "v"(sc[n][1]));
            asm("v_cvt_pk_bf16_f32 %0, %1, %2" : "=v"(w1) : "v"(sc[n][2]), "v"(sc[n][3]));
            uint2 wp; wp.x = w0; wp.y = w1;
            *reinterpret_cast<uint2*>(pw[n]) = wp;
        }

        // PV (swapped): oa[nd] += V^T-frag x P-frag
        bfv8 pa0 = *reinterpret_cast<const bfv8*>(pr0);
        bfv8 pa1 = *reinterpret_cast<const bfv8*>(pr1);
        __builtin_amdgcn_s_setprio(1);
#pragma unroll
        for (int nd = 0; nd < 4; nd++) {
            bfv8 v0 = ldsfrag(Vc, nd * 16 + c, g);
            bfv8 v1 = ldsfrag(Vc, nd * 16 + c, 4 + g);
            oa[nd] = mfma16(v0, pa0, oa[nd]);
            oa[nd] = mfma16(v1, pa1, oa[nd]);
        }
        __builtin_amdgcn_s_setprio(0);

        // row-sum (off critical path)
        float sn0 = (sc[0][0] + sc[0][1]) + (sc[0][2] + sc[0][3]);
        float sn1 = (sc[1][0] + sc[1][1]) + (sc[1][2] + sc[1][3]);
        float sn2 = (sc[2][0] + sc[2][1]) + (sc[2][2] + sc[2][3]);
        float sn3 = (sc[3][0] + sc[3][1]) + (sc[3][2] + sc[3][3]);
        float rs = (sn0 + sn1) + (sn2 + sn3);
        rs += __shfl_xor(rs, 16);
        rs += __shfl_xor(rs, 32);
        lrun += rs;

        // deferred-max safety check in pe-domain (2^11.5 = 2896)
        float t0 = fmaxf(max3f(sc[0][0], sc[0][1], sc[0][2]), sc[0][3]);
        float t1 = fmaxf(max3f(sc[1][0], sc[1][1], sc[1][2]), sc[1][3]);
        float t2 = fmaxf(max3f(sc[2][0], sc[2][1], sc[2][2]), sc[2][3]);
        float t3 = fmaxf(max3f(sc[3][0], sc[3][1], sc[3][2]), sc[3][3]);
        float pemax = fmaxf(max3f(t0, t1, t2), t3);
        if (!__all(pemax <= 2896.0f)) {   // rare: raise mrun, correct oa & lrun
            float rmax = fmaxf(pemax, __shfl_xor(pemax, 16));
            rmax = fmaxf(rmax, __shfl_xor(rmax, 32));
            if (rmax > 2896.0f) {
                const float corr = 1.0f / rmax;
                mrun += __log2f(rmax);
                lrun *= corr;
#pragma unroll
                for (int nd = 0; nd < 4; nd++)
#pragma unroll
                    for (int r = 0; r < 4; r++) oa[nd][r] *= corr;
            }
        }
        __syncthreads();
    }

    // epilogue: O^T frag -> Ob[B,S,1024], 8B stores
    const float rl = 1.f / lrun;
    const size_t srow = (size_t)(b * 2048 + q0 + c);
#pragma unroll
    for (int nd = 0; nd < 4; nd++) {
        s4v st;
#pragma unroll
        for (int r = 0; r < 4; r++) st[r] = f2bf(oa[nd][r] * rl);
        *reinterpret_cast<s4v*>(Ob + srow * 1024 + h * 64 + nd * 16 + 4 * g) = st;
    }
}

extern "C" void kernel_launch(void* const* d_in, const int* in_sizes, int n_in,
                              void* d_out, int out_size, void* d_ws, size_t ws_size,
                              hipStream_t stream)
{
    (void)in_sizes; (void)n_in; (void)out_size; (void)ws_size;
    const float* x    = (const float*)d_in[0];
    const float* bind = (const float*)d_in[1];
    const float* Wq   = (const float*)d_in[2];
    const float* bq   = (const float*)d_in[3];
    const float* Wk   = (const float*)d_in[4];
    const float* bk   = (const float*)d_in[5];
    const float* Wv   = (const float*)d_in[6];
    const float* bv   = (const float*)d_in[7];
    const float* Wo   = (const float*)d_in[8];
    const float* bo   = (const float*)d_in[9];

    char* ws = (char*)d_ws;
    const size_t MB = (size_t)1 << 20;
    short* xb   = (short*)(ws + 0 * MB);   // 8 MiB  x as bf16
    short* Wqt  = (short*)(ws + 8 * MB);   // 2 MiB  each, [n][k] bf16
    short* Wkt  = (short*)(ws + 10 * MB);
    short* Wvt  = (short*)(ws + 12 * MB);
    short* Wot  = (short*)(ws + 14 * MB);
    short* bbm  = (short*)(ws + 16 * MB);  // 8 MiB  0.5*log2e*binding bf16
    short* Qs   = (short*)(ws + 24 * MB);  // 8 MiB  [B,H,S,64]
    short* Kst  = (short*)(ws + 32 * MB);  // 8 MiB  [B,H,S,64]
    short* Vts  = (short*)(ws + 40 * MB);  // 8 MiB  [B,H,64,S]
    short* Obuf = (short*)(ws + 48 * MB);  // 8 MiB  [B,S,1024]

    const float LOG2E = 1.4426950408889634f;
    const float SCQ = 0.125f * LOG2E;   // hd^-0.5 * log2e, folded into Wq/bq
    const float SCB = 0.5f * LOG2E;     // binding_bias * log2e

    k_cvt<<<2048, 256, 0, stream>>>(x, xb, 1.f);
    k_cvt<<<2048, 256, 0, stream>>>(bind, bbm, SCB);
    k_transpose4<<<dim3(32, 32, 4), 256, 0, stream>>>(Wq, Wk, Wv, Wo,
                                                      Wqt, Wkt, Wvt, Wot, SCQ);
    k_gemm3<<<dim3(64, 24), 256, 0, stream>>>(xb, Wqt, Wkt, Wvt, bq, bk, bv,
                                              Qs, Kst, Vts, SCQ);
    k_attn<<<dim3(32, 32), 256, 0, stream>>>(Qs, Kst, Vts, bbm, Obuf);
    k_gemmO<<<dim3(64, 8), 256, 0, stream>>>(Obuf, Wot, bo, (float*)d_out);
}